// Round 1
// baseline (59.876 us; speedup 1.0000x reference)
//
#include <hip/hip_runtime.h>
#include <math.h>

// Problem constants (fixed by setup_inputs): B=32, 2P=2048.
#define BB 32
#define PP 1024
#define WW 2048   // 2*PP

// ws layout (floats):
//   [0..63]    S_b per (half h, row b): index h*32+b
//   [64..127]  per-row sum-of-squares partials (same indexing) -> T_h = sum of 32
//   [128..129] per-half sqrt-sum partials
// Total 130 floats = 520 B.

__device__ __forceinline__ float wave_reduce_sum(float v) {
    // wave64 shuffle reduction
    #pragma unroll
    for (int off = 32; off > 0; off >>= 1)
        v += __shfl_down(v, off, 64);
    return v;
}

// One block per (half, row): compute S_b and row sum-of-squares.
__global__ void k1_row_stats(const float* __restrict__ pred,
                             const float* __restrict__ truth,
                             float* __restrict__ ws) {
    const int bid = blockIdx.x;          // 0..63
    const int h = bid >> 5;              // half
    const int b = bid & 31;              // row
    const int base = b * WW + h * PP;
    const int t = threadIdx.x;           // 0..255

    float s = 0.f, q = 0.f;
    #pragma unroll
    for (int k = 0; k < 4; ++k) {
        const int j = t + k * 256;       // coalesced
        const float x = pred[base + j] - truth[base + j];
        s += x;
        q += x * x;
    }
    s = wave_reduce_sum(s);
    q = wave_reduce_sum(q);

    __shared__ float ls[4], lq[4];
    const int wave = t >> 6, lane = t & 63;
    if (lane == 0) { ls[wave] = s; lq[wave] = q; }
    __syncthreads();
    if (t == 0) {
        ws[bid]      = ls[0] + ls[1] + ls[2] + ls[3];
        ws[64 + bid] = lq[0] + lq[1] + lq[2] + lq[3];
    }
}

// One block per half; thread i = anchor i. D_i = T + P*Q_i - 2*R_i.
__global__ void k2_anchor(const float* __restrict__ pred,
                          const float* __restrict__ truth,
                          float* __restrict__ ws) {
    const int h = blockIdx.x;            // 0 or 1
    const int i = threadIdx.x;           // 0..1023

    // T_h from the 32 row partials (broadcast reads, L2-hot)
    float T = 0.f;
    #pragma unroll
    for (int k = 0; k < BB; ++k) T += ws[64 + h * 32 + k];

    __shared__ float Ssh[BB];
    if (i < BB) Ssh[i] = ws[h * 32 + i];
    __syncthreads();

    float q = 0.f, r = 0.f;
    #pragma unroll
    for (int b = 0; b < BB; ++b) {
        const int idx = b * WW + h * PP + i;   // coalesced across threads
        const float x = pred[idx] - truth[idx];
        q += x * x;
        r += x * Ssh[b];
    }
    const float D = T + (float)PP * q - 2.f * r;
    float s = sqrtf(fmaxf(D, 0.f));

    // block reduce over 16 waves
    s = wave_reduce_sum(s);
    __shared__ float lp[16];
    const int wave = i >> 6, lane = i & 63;
    if (lane == 0) lp[wave] = s;
    __syncthreads();
    if (i == 0) {
        float tot = 0.f;
        #pragma unroll
        for (int w = 0; w < 16; ++w) tot += lp[w];
        ws[128 + h] = tot;
    }
}

__global__ void k3_finish(const float* __restrict__ ws, float* __restrict__ out) {
    if (threadIdx.x == 0)
        out[0] = (ws[128] + ws[129]) * (1.0f / 64.0f);
}

extern "C" void kernel_launch(void* const* d_in, const int* in_sizes, int n_in,
                              void* d_out, int out_size, void* d_ws, size_t ws_size,
                              hipStream_t stream) {
    const float* pred  = (const float*)d_in[0];
    const float* truth = (const float*)d_in[1];
    float* ws  = (float*)d_ws;
    float* out = (float*)d_out;

    k1_row_stats<<<64, 256, 0, stream>>>(pred, truth, ws);
    k2_anchor<<<2, 1024, 0, stream>>>(pred, truth, ws);
    k3_finish<<<1, 64, 0, stream>>>(ws, out);
}